// Round 5
// baseline (438.662 us; speedup 1.0000x reference)
//
#include <hip/hip_runtime.h>
#include <stdint.h>

#define NS 150
#define D_IN 1024
#define D_H 512
#define D_OUT 256
#define BATCH 32

typedef float v2f __attribute__((ext_vector_type(2)));
typedef float v4f __attribute__((ext_vector_type(4)));

// ---- workspace layout (float offsets) ----
#define OFF_XT    0u                // 1024*32      = 32768   xT[i][b]
#define OFF_MS1   32768u            // float2[1024*512] (mu,std) at [i][h] -> 1048576 floats
#define OFF_MS2   1081344u          // float2[512*256]  (mu,std) at [hh][o] -> 262144 floats
#define OFF_B1S   1343488u          // 150*512  = 76800   b1s[n][h]
#define OFF_B2S   1420288u          // 150*256  = 38400   b2s[n][o]
#define OFF_HT    1458688u          // 150*512*32 = 2457600  hT[n][h][b]

// ---------- threefry-2x32 (JAX-exact, 20 rounds) ----------
__host__ __device__ __forceinline__ void threefry2x32(uint32_t k0, uint32_t k1,
                                                      uint32_t x0, uint32_t x1,
                                                      uint32_t& o0, uint32_t& o1) {
  uint32_t k2 = k0 ^ k1 ^ 0x1BD11BDAu;
  x0 += k0; x1 += k1;
#define TFR(r) { x0 += x1; x1 = (x1 << r) | (x1 >> (32 - r)); x1 ^= x0; }
  TFR(13) TFR(15) TFR(26) TFR(6)
  x0 += k1; x1 += k2 + 1u;
  TFR(17) TFR(29) TFR(16) TFR(24)
  x0 += k2; x1 += k0 + 2u;
  TFR(13) TFR(15) TFR(26) TFR(6)
  x0 += k0; x1 += k1 + 3u;
  TFR(17) TFR(29) TFR(16) TFR(24)
  x0 += k1; x1 += k2 + 4u;
  TFR(13) TFR(15) TFR(26) TFR(6)
  x0 += k2; x1 += k0 + 5u;
#undef TFR
  o0 = x0; o1 = x1;
}

// bits -> uniform(-1,1) -> sqrt2*erfinv; native log/sqrt; sqrt2 folded into coeffs
__device__ __forceinline__ float tf_normal(uint32_t k0, uint32_t k1, uint32_t idx) {
  uint32_t o0, o1;
  threefry2x32(k0, k1, 0u, idx, o0, o1);
  uint32_t bits = o0 ^ o1;
  uint32_t fb = (bits >> 9) | 0x3F800000u;
  float f = __uint_as_float(fb) - 1.0f;          // [0,1)
  const float lo = -0.99999994f;                 // nextafter(-1,0)
  float u = fmaf(f, 2.0f, lo);
  u = fmaxf(u, lo);
  float t = fmaf(u, -u, 1.0f);                   // 1-u^2, single rounding
  float w = -0.69314718056f * __builtin_amdgcn_logf(t);   // -ln(1-u^2)
  const float S = 1.41421354f;                   // folded at compile time
  float p;
  if (w < 5.0f) {
    float ww = w - 2.5f;
    p = S * 2.81022636e-08f;
    p = fmaf(p, ww, S * 3.43273939e-07f);
    p = fmaf(p, ww, S * -3.5233877e-06f);
    p = fmaf(p, ww, S * -4.39150654e-06f);
    p = fmaf(p, ww, S * 0.00021858087f);
    p = fmaf(p, ww, S * -0.00125372503f);
    p = fmaf(p, ww, S * -0.00417768164f);
    p = fmaf(p, ww, S * 0.246640727f);
    p = fmaf(p, ww, S * 1.50140941f);
  } else {
    float ww = __builtin_amdgcn_sqrtf(w) - 3.0f;
    p = S * -0.000200214257f;
    p = fmaf(p, ww, S * 0.000100950558f);
    p = fmaf(p, ww, S * 0.00134934322f);
    p = fmaf(p, ww, S * -0.00367342844f);
    p = fmaf(p, ww, S * 0.00573950773f);
    p = fmaf(p, ww, S * -0.0076224613f);
    p = fmaf(p, ww, S * 0.00943887047f);
    p = fmaf(p, ww, S * 1.00167406f);
    p = fmaf(p, ww, S * 2.83297682f);
  }
  return p * u;
}

// ---------- prep: LDS-tiled transposes into interleaved (mu,std) + biases ----------
__global__ __launch_bounds__(256) void prep_kernel(
    const float* __restrict__ x,
    const float* __restrict__ muW1, const float* __restrict__ vW1,
    const float* __restrict__ muW2, const float* __restrict__ vW2,
    const float* __restrict__ mub1, const float* __restrict__ vb1,
    const float* __restrict__ mub2, const float* __restrict__ vb2,
    float* __restrict__ ws,
    uint32_t kb1_0, uint32_t kb1_1, uint32_t kb2_0, uint32_t kb2_1) {
  __shared__ float2 tl[32][33];
  int bb = blockIdx.x;
  int tx = threadIdx.x & 31;
  int ty = threadIdx.x >> 5;        // 0..7

  if (bb < 512) {                   // W1 tile
    int i0 = (bb & 31) * 32, h0 = (bb >> 5) * 32;
#pragma unroll
    for (int r = 0; r < 4; ++r) {
      int h = h0 + ty + r * 8, i = i0 + tx;
      float m = muW1[h * D_IN + i];
      float s = expf(vW1[h * D_IN + i]);
      tl[ty + r * 8][tx] = make_float2(m, s);
    }
    __syncthreads();
    float2* ms1 = (float2*)(ws + OFF_MS1);
#pragma unroll
    for (int r = 0; r < 4; ++r) {
      int i = i0 + ty + r * 8, h = h0 + tx;
      ms1[i * D_H + h] = tl[tx][ty + r * 8];
    }
  } else if (bb < 640) {            // W2 tile
    int t = bb - 512;
    int h0 = (t & 15) * 32, o0 = (t >> 4) * 32;
#pragma unroll
    for (int r = 0; r < 4; ++r) {
      int o = o0 + ty + r * 8, hh = h0 + tx;
      float m = muW2[o * D_H + hh];
      float s = expf(vW2[o * D_H + hh]);
      tl[ty + r * 8][tx] = make_float2(m, s);
    }
    __syncthreads();
    float2* ms2 = (float2*)(ws + OFF_MS2);
#pragma unroll
    for (int r = 0; r < 4; ++r) {
      int hh = h0 + ty + r * 8, o = o0 + tx;
      ms2[hh * D_OUT + o] = tl[tx][ty + r * 8];
    }
  } else if (bb < 672) {            // xT tile
    int i0 = (bb - 640) * 32;
#pragma unroll
    for (int r = 0; r < 4; ++r) {
      int b = ty + r * 8, i = i0 + tx;
      tl[ty + r * 8][tx].x = x[b * D_IN + i];
    }
    __syncthreads();
#pragma unroll
    for (int r = 0; r < 4; ++r) {
      int i = i0 + ty + r * 8, b = tx;
      ws[OFF_XT + i * BATCH + b] = tl[tx][ty + r * 8].x;
    }
  } else if (bb < 747) {            // b1s
    int t0 = (bb - 672) * 1024 + threadIdx.x;
#pragma unroll
    for (int r = 0; r < 4; ++r) {
      int t = t0 + r * 256;
      int h = t & 511;
      float eps = tf_normal(kb1_0, kb1_1, (uint32_t)t);
      ws[OFF_B1S + t] = fmaf(eps, expf(vb1[h]), mub1[h]);
    }
  } else {                          // b2s
    int t0 = (bb - 747) * 1024 + threadIdx.x;
#pragma unroll
    for (int r = 0; r < 4; ++r) {
      int t = t0 + r * 256;
      if (t < NS * D_OUT) {
        int o = t & 255;
        float eps = tf_normal(kb2_0, kb2_1, (uint32_t)t);
        ws[OFF_B2S + t] = fmaf(eps, expf(vb2[o]), mub2[o]);
      }
    }
  }
}

// acc2[j] holds batch elements (2j, 2j+1)
#define GETB(b) (((b) & 1) ? acc2[(b) >> 1].y : acc2[(b) >> 1].x)

// ---------- layer 1: block = 512 thr = 8 waves; 64 (n,h)/block, 8 i-chunks of 128.
// bounds (512,6): VGPR cap 85 so the 32 accumulators stay in arch VGPRs
// (at (512,8)/cap-64 the allocator shuttled them through AGPRs: VGPR_Count=32,
// ~2x instruction stream). LDS 16 KiB, [chunk][b][lane] reduce = conflict-free.
__global__ __launch_bounds__(512, 6) void l1_kernel(
    const float* __restrict__ ws, float* __restrict__ hT,
    uint32_t k0, uint32_t k1) {
  const float* __restrict__ xT = ws + OFF_XT;
  const float2* __restrict__ ms1 = (const float2*)(ws + OFF_MS1);
  const float* __restrict__ b1s = ws + OFF_B1S;

  __shared__ float red[8][8][64];    // 16384 B

  int lane = threadIdx.x & 63;
  int wv = __builtin_amdgcn_readfirstlane(threadIdx.x >> 6);   // chunk 0..7
  int gid = blockIdx.x * 64 + lane;            // (n*512 + h)
  int h = gid & 511;

  v2f acc2[16];
#pragma unroll
  for (int j = 0; j < 16; ++j) acc2[j] = (v2f)(0.0f);

  uint32_t base = ((uint32_t)gid << 10) + (uint32_t)(wv * 128);
  int i0 = wv * 128;
#pragma unroll 2
  for (int ii = 0; ii < 128; ++ii) {
    int i = i0 + ii;                            // wave-uniform
    float2 ms = ms1[i * D_H + h];               // per-lane dwordx2, coalesced
    float eps = tf_normal(k0, k1, base + (uint32_t)ii);
    float wval = fmaf(eps, ms.y, ms.x);
    v2f wv2; wv2.x = wval; wv2.y = wval;
    const v4f* xp = (const v4f*)(xT + i * BATCH);   // wave-uniform addr
#pragma unroll
    for (int b4 = 0; b4 < 8; ++b4) {
      v4f xv = xp[b4];
      acc2[2 * b4]     = __builtin_elementwise_fma(wv2, xv.xy, acc2[2 * b4]);
      acc2[2 * b4 + 1] = __builtin_elementwise_fma(wv2, xv.zw, acc2[2 * b4 + 1]);
    }
  }

  float bb = b1s[gid];
#pragma unroll
  for (int p = 0; p < 4; ++p) {
#pragma unroll
    for (int j = 0; j < 8; ++j) red[wv][j][lane] = GETB(p * 8 + j);
    __syncthreads();
    float s = red[0][wv][lane] + red[1][wv][lane] + red[2][wv][lane] + red[3][wv][lane]
            + red[4][wv][lane] + red[5][wv][lane] + red[6][wv][lane] + red[7][wv][lane];
    hT[(size_t)gid * BATCH + p * 8 + wv] = fmaxf(s + bb, 0.0f);
    __syncthreads();
  }
}

// ---------- layer 2: block = 512 thr = 8 waves; 64 (n,o)/block, 8 hh-chunks of 64. ----------
__global__ __launch_bounds__(512, 6) void l2_kernel(
    const float* __restrict__ ws, float* __restrict__ y,
    uint32_t k0, uint32_t k1) {
  const float* __restrict__ hT = ws + OFF_HT;
  const float2* __restrict__ ms2 = (const float2*)(ws + OFF_MS2);
  const float* __restrict__ b2s = ws + OFF_B2S;

  __shared__ float red[8][8][64];    // 16384 B

  int lane = threadIdx.x & 63;
  int c = __builtin_amdgcn_readfirstlane(threadIdx.x >> 6);    // chunk 0..7
  int gid = blockIdx.x * 64 + lane;            // (n*256 + o)
  int n = __builtin_amdgcn_readfirstlane(gid >> 8);  // wave-uniform
  int o = gid & 255;

  v2f acc2[16];
#pragma unroll
  for (int j = 0; j < 16; ++j) acc2[j] = (v2f)(0.0f);

  uint32_t base = ((uint32_t)gid << 9) + (uint32_t)(c * 64);
  int h0 = c * 64;
  const float* hbase = hT + (size_t)n * (D_H * BATCH);
#pragma unroll 2
  for (int jj = 0; jj < 64; ++jj) {
    int hh = h0 + jj;                           // wave-uniform
    float2 ms = ms2[hh * D_OUT + o];            // per-lane, coalesced
    float eps = tf_normal(k0, k1, base + (uint32_t)jj);
    float wval = fmaf(eps, ms.y, ms.x);
    v2f wv2; wv2.x = wval; wv2.y = wval;
    const v4f* hp = (const v4f*)(hbase + hh * BATCH);   // wave-uniform addr
#pragma unroll
    for (int b4 = 0; b4 < 8; ++b4) {
      v4f hv = hp[b4];
      acc2[2 * b4]     = __builtin_elementwise_fma(wv2, hv.xy, acc2[2 * b4]);
      acc2[2 * b4 + 1] = __builtin_elementwise_fma(wv2, hv.zw, acc2[2 * b4 + 1]);
    }
  }

  float bb = b2s[gid];
#pragma unroll
  for (int p = 0; p < 4; ++p) {
#pragma unroll
    for (int j = 0; j < 8; ++j) red[c][j][lane] = GETB(p * 8 + j);
    __syncthreads();
    // thread (c,lane) reduces b = p*8 + c over the 8 chunks
    float s = red[0][c][lane] + red[1][c][lane] + red[2][c][lane] + red[3][c][lane]
            + red[4][c][lane] + red[5][c][lane] + red[6][c][lane] + red[7][c][lane];
    int b = p * 8 + c;
    y[(size_t)n * (BATCH * D_OUT) + b * D_OUT + o] = s + bb;   // coalesced (o inner)
    __syncthreads();
  }
}

extern "C" void kernel_launch(void* const* d_in, const int* in_sizes, int n_in,
                              void* d_out, int out_size, void* d_ws, size_t ws_size,
                              hipStream_t stream) {
  const float* x = (const float*)d_in[0];
  const float* muW1 = (const float*)d_in[1];
  const float* mub1 = (const float*)d_in[2];
  const float* muW2 = (const float*)d_in[3];
  const float* mub2 = (const float*)d_in[4];
  const float* vW1 = (const float*)d_in[5];
  const float* vb1 = (const float*)d_in[6];
  const float* vW2 = (const float*)d_in[7];
  const float* vb2 = (const float*)d_in[8];
  float* y = (float*)d_out;
  float* ws = (float*)d_ws;

  uint32_t nk[4][2];
  for (uint32_t j = 0; j < 4; ++j) {
    threefry2x32(0u, 42u, 0u, j, nk[j][0], nk[j][1]);
  }
  // eW1=nk[0], eb1=nk[1], eW2=nk[2], eb2=nk[3]

  prep_kernel<<<785, 256, 0, stream>>>(
      x, muW1, vW1, muW2, vW2, mub1, vb1, mub2, vb2, ws,
      nk[1][0], nk[1][1], nk[3][0], nk[3][1]);

  // l1: 76800 (n,h) pairs, 64/block, 8 i-chunks -> 1200 blocks x 512
  l1_kernel<<<NS * D_H / 64, 512, 0, stream>>>(ws, ws + OFF_HT, nk[0][0], nk[0][1]);

  // l2: 38400 (n,o) pairs, 64/block, 8 hh-chunks -> 600 blocks x 512
  l2_kernel<<<NS * D_OUT / 64, 512, 0, stream>>>(ws, y, nk[2][0], nk[2][1]);
}